// Round 1
// baseline (1263.480 us; speedup 1.0000x reference)
//
#include <hip/hip_runtime.h>
#include <hip/hip_bf16.h>
#include <math.h>

#define DM 768
#define NBATCH 2
#define TIMEN 196
#define SPACEF 8
#define SEQL 1569          // 1 + 196*8
#define NSTATE 16
#define MT 3136            // mamba tokens = 2*196*8
#define NSEQ 392           // mamba sequences = 2*196, each length 8
#define AT 3152            // attn tokens = 16*197
#define XTOK 3138          // 2*1569

__device__ __forceinline__ float siluf(float x){ return x / (1.0f + expf(-x)); }
__device__ __forceinline__ float geluf(float x){ return 0.5f*x*(1.0f + erff(x*0.70710678118654752f)); }
__device__ __forceinline__ float softplusf(float x){ return (x > 20.0f) ? x : log1pf(expf(x)); }

__device__ __forceinline__ float block_sum256(float v, float* sm){
  #pragma unroll
  for (int o = 32; o > 0; o >>= 1) v += __shfl_down(v, o);
  __syncthreads();
  if ((threadIdx.x & 63) == 0) sm[threadIdx.x >> 6] = v;
  __syncthreads();
  return sm[0] + sm[1] + sm[2] + sm[3];
}

// mode 0: contiguous rows of src0
// mode 1: xt gather from x (skip row 0 of each batch)
// mode 2: xs gather (cls from x row0 of batch, else time_res transpose)
__global__ __launch_bounds__(256) void ln_kernel(
    const float* __restrict__ src0, const float* __restrict__ src1,
    const float* __restrict__ w, const float* __restrict__ b,
    float* __restrict__ out, int mode)
{
  __shared__ float sm[4];
  int tok = blockIdx.x;
  const float* src;
  if (mode == 0) {
    src = src0 + (size_t)tok * DM;
  } else if (mode == 1) {
    int bi = tok / (TIMEN*SPACEF), r = tok % (TIMEN*SPACEF);
    src = src0 + ((size_t)bi * SEQL + 1 + r) * DM;
  } else {
    int sidx = tok / 197, p = tok % 197;
    if (p == 0) src = src0 + (size_t)(sidx >> 3) * SEQL * DM;
    else { int bi = sidx >> 3, f = sidx & 7, t = p - 1;
           src = src1 + (size_t)((bi*TIMEN + t)*SPACEF + f) * DM; }
  }
  int tid = threadIdx.x;
  float xr[3];
  #pragma unroll
  for (int i = 0; i < 3; i++) xr[i] = src[tid + i*256];
  float mean = block_sum256(xr[0]+xr[1]+xr[2], sm) * (1.0f/768.0f);
  float v0 = xr[0]-mean, v1 = xr[1]-mean, v2 = xr[2]-mean;
  float var = block_sum256(v0*v0 + v1*v1 + v2*v2, sm) * (1.0f/768.0f);
  float rstd = rsqrtf(var + 1e-5f);
  float* o = out + (size_t)tok * DM;
  #pragma unroll
  for (int i = 0; i < 3; i++){ int c = tid + i*256; o[c] = (xr[i]-mean)*rstd*w[c] + b[c]; }
}

// C[M,N] = act( A[M,K](row-stride lda) @ W[N,K]^T + bias ) + residual
// act: 0 none, 1 gelu, 2 softplus ; resmode: 0 none, 1 plain rows of resid, 2 xt-gather from resid(=x)
#define BM 64
#define BN 64
#define BKT 16
__global__ __launch_bounds__(256) void gemm_kernel(
    const float* __restrict__ A, int lda,
    const float* __restrict__ W,
    const float* __restrict__ bias,
    const float* __restrict__ resid,
    float* __restrict__ C,
    int M, int N, int K, int act, int resmode)
{
  __shared__ float As[BKT][BM];
  __shared__ float Bs[BKT][BN];
  int tid = threadIdx.x;
  int m0 = blockIdx.y * BM, n0 = blockIdx.x * BN;
  int tx = tid & 15, ty = tid >> 4;
  int lr = tid >> 2, lc = (tid & 3) * 4;   // loader: row lr, k-cols lc..lc+3
  float acc[4][4] = {};
  for (int k0 = 0; k0 < K; k0 += BKT) {
    float4 av = make_float4(0,0,0,0), bv = make_float4(0,0,0,0);
    if (m0 + lr < M) av = *(const float4*)(A + (size_t)(m0+lr)*lda + k0 + lc);
    if (n0 + lr < N) bv = *(const float4*)(W + (size_t)(n0+lr)*K + k0 + lc);
    As[lc+0][lr] = av.x; As[lc+1][lr] = av.y; As[lc+2][lr] = av.z; As[lc+3][lr] = av.w;
    Bs[lc+0][lr] = bv.x; Bs[lc+1][lr] = bv.y; Bs[lc+2][lr] = bv.z; Bs[lc+3][lr] = bv.w;
    __syncthreads();
    #pragma unroll
    for (int kk = 0; kk < BKT; kk++) {
      float4 a4 = *(const float4*)&As[kk][ty*4];
      float4 b4 = *(const float4*)&Bs[kk][tx*4];
      float a[4] = {a4.x,a4.y,a4.z,a4.w};
      float bb[4] = {b4.x,b4.y,b4.z,b4.w};
      #pragma unroll
      for (int i = 0; i < 4; i++)
        #pragma unroll
        for (int j = 0; j < 4; j++) acc[i][j] += a[i]*bb[j];
    }
    __syncthreads();
  }
  #pragma unroll
  for (int i = 0; i < 4; i++) {
    int m = m0 + ty*4 + i;
    if (m >= M) continue;
    #pragma unroll
    for (int j = 0; j < 4; j++) {
      int n = n0 + tx*4 + j;
      if (n >= N) continue;
      float v = acc[i][j];
      if (bias) v += bias[n];
      if (act == 1) v = geluf(v);
      else if (act == 2) v = softplusf(v);
      if (resmode == 1) v += resid[(size_t)m*N + n];
      else if (resmode == 2) {
        int bi = m / (TIMEN*SPACEF), r = m % (TIMEN*SPACEF);
        v += resid[((size_t)bi*SEQL + 1 + r)*DM + n];
      }
      C[(size_t)m*N + n] = v;
    }
  }
}

// causal conv (D_CONV=4) + silu, both directions. backward stored in FLIPPED coords.
__global__ __launch_bounds__(256) void conv_kernel(
    const float* __restrict__ xz,
    const float* __restrict__ wf, const float* __restrict__ bf,
    const float* __restrict__ wb, const float* __restrict__ bb,
    float* __restrict__ xcf, float* __restrict__ xcb)
{
  int g = blockIdx.x*256 + threadIdx.x;
  if (g >= NSEQ*DM) return;
  int s = g / DM, d = g % DM;
  float xr[8];
  #pragma unroll
  for (int j = 0; j < 8; j++) xr[j] = xz[(size_t)(s*8 + j)*1536 + d];
  float wfv[4], wbv[4];
  #pragma unroll
  for (int k = 0; k < 4; k++){ wfv[k] = wf[d*4+k]; wbv[k] = wb[d*4+k]; }
  float bfv = bf[d], bbv = bb[d];
  #pragma unroll
  for (int l = 0; l < 8; l++) {
    float af = bfv, ab = bbv;
    #pragma unroll
    for (int k = 0; k < 4; k++) {
      if (l + k >= 3) {
        af += wfv[k] * xr[l + k - 3];      // forward causal
        ab += wbv[k] * xr[10 - l - k];     // flipped-seq causal
      }
    }
    xcf[(size_t)(s*8 + l)*DM + d] = siluf(af);
    xcb[(size_t)(s*8 + l)*DM + d] = siluf(ab);
  }
}

__global__ __launch_bounds__(256) void ssm_kernel(
    const float* __restrict__ xz,
    const float* __restrict__ xcf, const float* __restrict__ xcb,
    const float* __restrict__ dblf, const float* __restrict__ dblb,
    const float* __restrict__ dlf, const float* __restrict__ dlb,
    const float* __restrict__ Alogf, const float* __restrict__ Df,
    const float* __restrict__ Alogb, const float* __restrict__ Db,
    float* __restrict__ y)
{
  int s = blockIdx.y;
  int d = blockIdx.x*256 + threadIdx.x;
  int tid = threadIdx.x;
  float Af[NSTATE], Ab[NSTATE];
  #pragma unroll
  for (int n = 0; n < NSTATE; n++) {
    Af[n] = -expf(Alogf[d*NSTATE + n]);
    Ab[n] = -expf(Alogb[d*NSTATE + n]);
  }
  float Dfv = Df[d], Dbv = Db[d];
  float hf[NSTATE] = {}, hb[NSTATE] = {};
  float yf[8], yb[8];
  __shared__ float sBf[16], sCf[16], sBb[16], sCb[16];
  for (int l = 0; l < 8; l++) {
    int t = s*8 + l;
    __syncthreads();
    if (tid < 16)      sBf[tid]    = dblf[(size_t)t*80 + 48 + tid];
    else if (tid < 32) sCf[tid-16] = dblf[(size_t)t*80 + 64 + (tid-16)];
    else if (tid < 48) sBb[tid-32] = dblb[(size_t)t*80 + 48 + (tid-32)];
    else if (tid < 64) sCb[tid-48] = dblb[(size_t)t*80 + 64 + (tid-48)];
    __syncthreads();
    float delf = dlf[(size_t)t*DM + d], uf = xcf[(size_t)t*DM + d];
    float accf = 0.0f;
    #pragma unroll
    for (int n = 0; n < NSTATE; n++) {
      hf[n] = expf(delf*Af[n])*hf[n] + delf*uf*sBf[n];
      accf += hf[n]*sCf[n];
    }
    yf[l] = accf + uf*Dfv;
    float delb = dlb[(size_t)t*DM + d], ub = xcb[(size_t)t*DM + d];
    float accb = 0.0f;
    #pragma unroll
    for (int n = 0; n < NSTATE; n++) {
      hb[n] = expf(delb*Ab[n])*hb[n] + delb*ub*sBb[n];
      accb += hb[n]*sCb[n];
    }
    yb[7-l] = accb + ub*Dbv;   // flipped coords -> original position 7-l
  }
  #pragma unroll
  for (int l = 0; l < 8; l++) {
    int t = s*8 + l;
    float zv = xz[(size_t)t*1536 + DM + d];
    y[(size_t)t*DM + d] = (yf[l] + yb[l]) * siluf(zv);
  }
}

__global__ __launch_bounds__(256) void attn_kernel(
    const float* __restrict__ qkv, float* __restrict__ ao)
{
  int n = blockIdx.x / 12, h = blockIdx.x % 12;
  __shared__ float qs[16][65], ks[16][65], vs[16][65], ps[16][17];
  int tid = threadIdx.x;
  for (int e = tid; e < 1024; e += 256) {
    int l = e >> 6, c = e & 63;
    size_t row = ((size_t)l*197 + n)*2304 + h*64 + c;
    qs[l][c] = qkv[row];
    ks[l][c] = qkv[row + 768];
    vs[l][c] = qkv[row + 1536];
  }
  __syncthreads();
  int l = tid >> 4, m = tid & 15;
  float sc = 0.0f;
  #pragma unroll
  for (int c = 0; c < 64; c++) sc += qs[l][c]*ks[m][c];
  sc *= 0.125f;
  float mx = sc;
  #pragma unroll
  for (int o = 8; o > 0; o >>= 1) mx = fmaxf(mx, __shfl_xor(mx, o, 16));
  float p = expf(sc - mx);
  float smv = p;
  #pragma unroll
  for (int o = 8; o > 0; o >>= 1) smv += __shfl_xor(smv, o, 16);
  ps[l][m] = p / smv;
  __syncthreads();
  for (int e = tid; e < 1024; e += 256) {
    int ll = e >> 6, c = e & 63;
    float acc = 0.0f;
    #pragma unroll
    for (int mm = 0; mm < 16; mm++) acc += ps[ll][mm]*vs[mm][c];
    ao[((size_t)ll*197 + n)*768 + h*64 + c] = acc;
  }
}

// x_new = x + scatter(space_out); row0 gets mean over f of cls outputs
__global__ __launch_bounds__(256) void scatter_kernel(
    const float* __restrict__ x, const float* __restrict__ so,
    float* __restrict__ xnew)
{
  int idx = blockIdx.x*256 + threadIdx.x;
  if (idx >= NBATCH*SEQL*DM) return;
  int bi = idx / (SEQL*DM);
  int rem = idx % (SEQL*DM);
  int row = rem / DM, d = rem % DM;
  float v;
  if (row == 0) {
    float acc = 0.0f;
    #pragma unroll
    for (int f = 0; f < SPACEF; f++)
      acc += so[((size_t)(bi*SPACEF + f)*197)*DM + d];
    v = x[idx] + acc * 0.125f;
  } else {
    int t = (row - 1) >> 3, f = (row - 1) & 7;
    v = x[idx] + so[((size_t)(bi*SPACEF + f)*197 + 1 + t)*DM + d];
  }
  xnew[idx] = v;
}

extern "C" void kernel_launch(void* const* d_in, const int* in_sizes, int n_in,
                              void* d_out, int out_size, void* d_ws, size_t ws_size,
                              hipStream_t stream) {
  const float* x        = (const float*)d_in[0];
  const float* norm1_w  = (const float*)d_in[1];
  const float* norm1_b  = (const float*)d_in[2];
  const float* norm2_w  = (const float*)d_in[3];
  const float* norm2_b  = (const float*)d_in[4];
  const float* norm3_w  = (const float*)d_in[5];
  const float* norm3_b  = (const float*)d_in[6];
  const float* attn_in_w  = (const float*)d_in[7];
  const float* attn_in_b  = (const float*)d_in[8];
  const float* attn_out_w = (const float*)d_in[9];
  const float* attn_out_b = (const float*)d_in[10];
  const float* m_in_w   = (const float*)d_in[11];
  const float* m_conv_w = (const float*)d_in[12];
  const float* m_conv_b = (const float*)d_in[13];
  const float* m_xproj_w= (const float*)d_in[14];
  const float* m_dt_w   = (const float*)d_in[15];
  const float* m_dt_b   = (const float*)d_in[16];
  const float* m_Alog   = (const float*)d_in[17];
  const float* m_D      = (const float*)d_in[18];
  const float* m_conv_wb= (const float*)d_in[19];
  const float* m_conv_bb= (const float*)d_in[20];
  const float* m_xproj_wb=(const float*)d_in[21];
  const float* m_dt_wb  = (const float*)d_in[22];
  const float* m_dt_bb  = (const float*)d_in[23];
  const float* m_Alog_b = (const float*)d_in[24];
  const float* m_D_b    = (const float*)d_in[25];
  const float* m_out_w  = (const float*)d_in[26];
  const float* fc1_w    = (const float*)d_in[27];
  const float* fc1_b    = (const float*)d_in[28];
  const float* fc2_w    = (const float*)d_in[29];
  const float* fc2_b    = (const float*)d_in[30];

  float* ws = (float*)d_ws;
  // phase 1 layout
  const size_t off_xz   = 0;                       // 3136*1536
  const size_t off_xcf  = off_xz  + (size_t)MT*1536;   // 3136*768 (also ln3)
  const size_t off_xcb  = off_xcf + (size_t)MT*DM;
  const size_t off_dblf = off_xcb + (size_t)MT*DM;     // 3136*80
  const size_t off_dblb = off_dblf + (size_t)MT*80;
  const size_t off_dlf  = off_dblb + (size_t)MT*80;    // 3136*768
  const size_t off_dlb  = off_dlf + (size_t)MT*DM;
  const size_t off_y    = off_dlb + (size_t)MT*DM;
  const size_t off_tres = off_y   + (size_t)MT*DM;     // kept through phase 2
  // phase 2 layout (reuses phase-1 space below off_tres except y)
  const size_t off_xsln = 0;                            // 3152*768
  const size_t off_qkv  = off_xsln + (size_t)AT*DM;     // 3152*2304
  const size_t off_ao   = off_qkv + (size_t)AT*2304;    // 3152*768
  const size_t off_so   = off_ao  + (size_t)AT*DM;      // 3152*768
  const size_t off_xnew = off_y;                        // 3138*768 (y dead by now)
  // phase 3 layout
  const size_t off_ln2  = 0;                            // 3138*768
  const size_t off_h1   = off_ln2 + (size_t)XTOK*DM;    // 3138*3072

  // ===== phase 1: mamba over time tokens =====
  ln_kernel<<<MT, 256, 0, stream>>>(x, nullptr, norm3_w, norm3_b, ws + off_xcf, 1);
  gemm_kernel<<<dim3(1536/64, (MT+63)/64), 256, 0, stream>>>(
      ws + off_xcf, DM, m_in_w, nullptr, nullptr, ws + off_xz, MT, 1536, DM, 0, 0);
  conv_kernel<<<(NSEQ*DM + 255)/256, 256, 0, stream>>>(
      ws + off_xz, m_conv_w, m_conv_b, m_conv_wb, m_conv_bb, ws + off_xcf, ws + off_xcb);
  gemm_kernel<<<dim3(2, (MT+63)/64), 256, 0, stream>>>(
      ws + off_xcf, DM, m_xproj_w, nullptr, nullptr, ws + off_dblf, MT, 80, DM, 0, 0);
  gemm_kernel<<<dim3(2, (MT+63)/64), 256, 0, stream>>>(
      ws + off_xcb, DM, m_xproj_wb, nullptr, nullptr, ws + off_dblb, MT, 80, DM, 0, 0);
  gemm_kernel<<<dim3(12, (MT+63)/64), 256, 0, stream>>>(
      ws + off_dblf, 80, m_dt_w, m_dt_b, nullptr, ws + off_dlf, MT, DM, 48, 2, 0);
  gemm_kernel<<<dim3(12, (MT+63)/64), 256, 0, stream>>>(
      ws + off_dblb, 80, m_dt_wb, m_dt_bb, nullptr, ws + off_dlb, MT, DM, 48, 2, 0);
  ssm_kernel<<<dim3(3, NSEQ), 256, 0, stream>>>(
      ws + off_xz, ws + off_xcf, ws + off_xcb, ws + off_dblf, ws + off_dblb,
      ws + off_dlf, ws + off_dlb, m_Alog, m_D, m_Alog_b, m_D_b, ws + off_y);
  gemm_kernel<<<dim3(12, (MT+63)/64), 256, 0, stream>>>(
      ws + off_y, DM, m_out_w, nullptr, x, ws + off_tres, MT, DM, DM, 0, 2);

  // ===== phase 2: attention over space =====
  ln_kernel<<<AT, 256, 0, stream>>>(x, ws + off_tres, norm1_w, norm1_b, ws + off_xsln, 2);
  gemm_kernel<<<dim3(2304/64, (AT+63)/64), 256, 0, stream>>>(
      ws + off_xsln, DM, attn_in_w, attn_in_b, nullptr, ws + off_qkv, AT, 2304, DM, 0, 0);
  attn_kernel<<<197*12, 256, 0, stream>>>(ws + off_qkv, ws + off_ao);
  gemm_kernel<<<dim3(12, (AT+63)/64), 256, 0, stream>>>(
      ws + off_ao, DM, attn_out_w, attn_out_b, nullptr, ws + off_so, AT, DM, DM, 0, 0);
  scatter_kernel<<<(NBATCH*SEQL*DM + 255)/256, 256, 0, stream>>>(
      x, ws + off_so, ws + off_xnew);

  // ===== phase 3: MLP =====
  ln_kernel<<<XTOK, 256, 0, stream>>>(ws + off_xnew, nullptr, norm2_w, norm2_b, ws + off_ln2, 0);
  gemm_kernel<<<dim3(3072/64, (XTOK+63)/64), 256, 0, stream>>>(
      ws + off_ln2, DM, fc1_w, fc1_b, nullptr, ws + off_h1, XTOK, 3072, DM, 1, 0);
  gemm_kernel<<<dim3(12, (XTOK+63)/64), 256, 0, stream>>>(
      ws + off_h1, 3072, fc2_w, fc2_b, ws + off_xnew, (float*)d_out, XTOK, DM, 3072, 0, 1);
}